// Round 2
// baseline (1199.343 us; speedup 1.0000x reference)
//
#include <hip/hip_runtime.h>
#include <hip/hip_bf16.h>
#include <stdint.h>

#define B_ 64
#define T_ 128
#define L_ 32
#define D_ 128
#define K_ 64

// workspace offsets in 4-byte units
#define FLAG_OFF 0
#define SM_OFF   256
#define ENC_OFF  (SM_OFF + B_*T_)                 // [B][T][D] f32
#define SW_OFF   (ENC_OFF + B_*T_*D_)             // [B][T][D] f32  (s @ Ww)
#define KS_OFF   (SW_OFF + B_*T_*D_)              // [B][T][K] f32  (keys . s)
#define KV_OFF   (KS_OFF + B_*T_*K_)              // [B][K][D] f32  (keys @ Vw)
#define UB_OFF   (KV_OFF + B_*K_*D_)              // [D][D/2] packed bf16 pairs (8192 u32)

__device__ __forceinline__ float sigmoidf_(float x){ return 1.0f/(1.0f + __expf(-x)); }

__device__ __forceinline__ unsigned short f2bf(float f){
  unsigned u = __float_as_uint(f);
  unsigned r = (u + 0x7fffu + ((u>>16)&1u)) >> 16;   // RNE
  return (unsigned short)r;
}

// --- K0: detect whether prgrph_mask arrived as 1-byte bool or 4-byte int32 ---
__global__ void k_detect(const uint8_t* m, int* flag){
  __shared__ int f;
  if(threadIdx.x==0) f = 0;
  __syncthreads();
  int loc = 0;
  for(int i = threadIdx.x; i < B_*T_*L_; i += blockDim.x){
    if((i&3)!=0 && m[i]!=0) loc = 1;   // int32 0/1 masks have zero bytes here
  }
  if(loc) atomicOr(&f, 1);
  __syncthreads();
  if(threadIdx.x==0) *flag = f;        // 1 => bool bytes, 0 => int32
}

// --- K1: per (b,t): enc row, SW = enc@Ww, KS = keys.enc, sent_mask ---
__global__ __launch_bounds__(128) void k_enc(const int* __restrict__ prg,
                                             const uint8_t* __restrict__ pm8,
                                             const float* __restrict__ emb,
                                             const float* __restrict__ pos,
                                             const float* __restrict__ Ww,
                                             const float* __restrict__ keys,
                                             float* __restrict__ W){
  const int flag = ((const int*)W)[FLAG_OFF];
  const int bt = blockIdx.x;
  const int b  = bt / T_;
  const int d  = threadIdx.x;
  __shared__ float keysl[K_*129];
  __shared__ float encl[D_];
  // stage keys[b]  (pad 129 -> conflict-free row reads in KS)
  for(int r=0;r<K_;r++) keysl[r*129 + d] = keys[(b*K_ + r)*D_ + d];
  const int* pmi = (const int*)pm8;
  float acc = 0.f; int anym = 0;
  for(int l=0;l<L_;l++){
    int off = bt*L_ + l;
    int m = flag ? (int)pm8[off] : pmi[off];
    if(m){            // uniform branch
      anym = 1;
      int idx = prg[off];
      acc += emb[idx*D_ + d] * pos[l*D_ + d];
    }
  }
  encl[d] = acc;
  W[ENC_OFF + bt*D_ + d] = acc;
  __syncthreads();
  float sw = 0.f;
  for(int e=0;e<D_;e++) sw += encl[e] * Ww[e*D_ + d];
  W[SW_OFF + bt*D_ + d] = sw;
  if(d < K_){
    float ks = 0.f;
    for(int dd=0;dd<D_;dd++) ks += keysl[d*129 + dd] * encl[dd];
    W[KS_OFF + bt*K_ + d] = ks;
  }
  if(d==0) W[SM_OFF + bt] = anym ? 1.f : 0.f;
}

// --- K2: KV = keys @ Vw ---
__global__ __launch_bounds__(128) void k_kv(const float* __restrict__ keys,
                                            const float* __restrict__ Vw,
                                            float* __restrict__ W){
  const int bk = blockIdx.x;
  const int d  = threadIdx.x;
  __shared__ float kr[D_];
  kr[d] = keys[bk*D_ + d];
  __syncthreads();
  float acc = 0.f;
  for(int e=0;e<D_;e++) acc += kr[e] * Vw[e*D_ + d];
  W[KV_OFF + bk*D_ + d] = acc;
}

// --- K2b: Uw -> packed bf16 ---
__global__ void k_u16(const float* __restrict__ Uw, float* __restrict__ W){
  unsigned* ub = (unsigned*)&W[UB_OFF];
  int i = blockIdx.x*blockDim.x + threadIdx.x;
  if(i < D_*D_/2){
    unsigned lo = (unsigned)f2bf(Uw[2*i]);
    unsigned hi = (unsigned)f2bf(Uw[2*i+1]);
    ub[i] = (hi<<16) | lo;
  }
}

// --- K3: the scan. grid = 64 b x 4 kgroups; block = 256 thr = 16 pairs x 16 lanes ---
__global__ __launch_bounds__(256) void k_scan(const float* __restrict__ W,
                                              float* __restrict__ out){
  const int b   = blockIdx.x >> 2;
  const int kg  = blockIdx.x & 3;
  const int tid = threadIdx.x;
  const int p   = tid >> 4;      // entity within block (0..15)
  const int i   = tid & 15;      // lane within entity; owns e in [8i, 8i+8)
  const int kglob = kg*16 + p;

  __shared__ unsigned Ub[D_*D_/2];      // 32 KB bf16 U, row-major [128][64 u32]
  __shared__ float hl[16*136];          // h state, padded rows (136*4B = 16B-mult)
  __shared__ float sl[D_], swl[D_], ksl[K_];

  { // stage U once
    const uint4* src = (const uint4*)((const unsigned*)&W[UB_OFF]);
    uint4* dst = (uint4*)Ub;
    for(int it=tid; it<D_*D_/8; it+=256) dst[it] = src[it];
  }
  float h[8];
  #pragma unroll
  for(int j=0;j<8;j++) h[j] = 0.f;
  #pragma unroll
  for(int j=0;j<8;j++) hl[p*136 + 8*i + j] = 0.f;
  float kv[8];
  {
    const float* KVr = &W[KV_OFF + (b*K_ + kglob)*D_ + 8*i];
    #pragma unroll
    for(int j=0;j<8;j++) kv[j] = KVr[j];
  }
  __syncthreads();

  const float* ENC = &W[ENC_OFF + b*T_*D_];
  const float* SWg = &W[SW_OFF  + b*T_*D_];
  const float* KSg = &W[KS_OFF  + b*T_*K_];
  const float* SM  = &W[SM_OFF  + b*T_];

  for(int t=0;t<T_;t++){
    if(tid < 128) sl[tid]      = ENC[t*D_ + tid];
    else          swl[tid-128] = SWg[t*D_ + tid-128];
    if(tid < 64)  ksl[tid]     = KSg[t*K_ + tid];
    float m = SM[t];
    __syncthreads();
    if(m != 0.f){
      // gate: sigmoid(h.s + keys.s)
      float gs = 0.f;
      #pragma unroll
      for(int j=0;j<8;j++) gs += h[j]*sl[8*i+j];
      #pragma unroll
      for(int s=1;s<16;s<<=1) gs += __shfl_xor(gs, s);
      float g = sigmoidf_(gs + ksl[kglob]);
      // hU = h . Uw  (bf16 U from LDS)
      float acc[8];
      #pragma unroll
      for(int j=0;j<8;j++) acc[j] = 0.f;
      #pragma unroll 4
      for(int dd=0;dd<D_;dd++){
        float hv = hl[p*136 + dd];
        uint4 uu = *((const uint4*)&Ub[dd*64 + 4*i]);
        acc[0] = fmaf(hv, __uint_as_float(uu.x<<16),          acc[0]);
        acc[1] = fmaf(hv, __uint_as_float(uu.x & 0xffff0000u), acc[1]);
        acc[2] = fmaf(hv, __uint_as_float(uu.y<<16),          acc[2]);
        acc[3] = fmaf(hv, __uint_as_float(uu.y & 0xffff0000u), acc[3]);
        acc[4] = fmaf(hv, __uint_as_float(uu.z<<16),          acc[4]);
        acc[5] = fmaf(hv, __uint_as_float(uu.z & 0xffff0000u), acc[5]);
        acc[6] = fmaf(hv, __uint_as_float(uu.w<<16),          acc[6]);
        acc[7] = fmaf(hv, __uint_as_float(uu.w & 0xffff0000u), acc[7]);
      }
      // update + normalize
      float hn[8]; float nrm = 0.f;
      #pragma unroll
      for(int j=0;j<8;j++){
        float x  = acc[j] + kv[j] + swl[8*i+j];
        float ht = sigmoidf_(x);
        hn[j] = h[j] + g*ht;
        nrm += hn[j]*hn[j];
      }
      #pragma unroll
      for(int s=1;s<16;s<<=1) nrm += __shfl_xor(nrm, s);
      float rn = 1.0f / sqrtf(fmaxf(nrm, 1e-12f));
      #pragma unroll
      for(int j=0;j<8;j++) h[j] = hn[j]*rn;
      #pragma unroll
      for(int j=0;j<8;j++) hl[p*136 + 8*i + j] = h[j];
    }
    __syncthreads();
  }
  float4* o = (float4*)&out[(b*K_ + kglob)*D_ + 8*i];
  o[0] = make_float4(h[0],h[1],h[2],h[3]);
  o[1] = make_float4(h[4],h[5],h[6],h[7]);
}

extern "C" void kernel_launch(void* const* d_in, const int* in_sizes, int n_in,
                              void* d_out, int out_size, void* d_ws, size_t ws_size,
                              hipStream_t stream) {
  const int*     prg  = (const int*)d_in[0];
  const uint8_t* pm   = (const uint8_t*)d_in[1];
  const float*   emb  = (const float*)d_in[2];
  const float*   pos  = (const float*)d_in[3];
  const float*   Uw   = (const float*)d_in[4];
  const float*   Vw   = (const float*)d_in[5];
  const float*   Ww   = (const float*)d_in[6];
  const float*   keys = (const float*)d_in[7];
  float* W   = (float*)d_ws;
  float* out = (float*)d_out;

  hipLaunchKernelGGL(k_detect, dim3(1),      dim3(256), 0, stream, pm, (int*)d_ws);
  hipLaunchKernelGGL(k_enc,    dim3(B_*T_),  dim3(128), 0, stream, prg, pm, emb, pos, Ww, keys, W);
  hipLaunchKernelGGL(k_kv,     dim3(B_*K_),  dim3(128), 0, stream, keys, Vw, W);
  hipLaunchKernelGGL(k_u16,    dim3(32),     dim3(256), 0, stream, Uw, W);
  hipLaunchKernelGGL(k_scan,   dim3(B_*4),   dim3(256), 0, stream, W, out);
}

// Round 3
// 809.417 us; speedup vs baseline: 1.4817x; 1.4817x over previous
//
#include <hip/hip_runtime.h>
#include <hip/hip_bf16.h>
#include <stdint.h>

#define B_ 64
#define T_ 128
#define L_ 32
#define D_ 128
#define K_ 64

// workspace offsets in 4-byte units
#define FLAG_OFF 0
#define SM_OFF   256
#define ENC_OFF  (SM_OFF + B_*T_)                 // [B][T][D] f32
#define SW_OFF   (ENC_OFF + B_*T_*D_)             // [B][T][D] f32  (s @ Ww)
#define KS_OFF   (SW_OFF + B_*T_*D_)              // [B][T][K] f32  (keys . s)
#define KV_OFF   (KS_OFF + B_*T_*K_)              // [B][K][D] f32  (keys @ Vw)

typedef __attribute__((ext_vector_type(8))) short short8b;   // 8 bf16 = 4 VGPR
typedef __attribute__((ext_vector_type(4))) float f32x4;

__device__ __forceinline__ float sigmoidf_(float x){ return 1.0f/(1.0f + __expf(-x)); }

__device__ __forceinline__ unsigned short bfb(float x){
  __hip_bfloat16 h = __float2bfloat16(x);                    // RNE
  return __builtin_bit_cast(unsigned short, h);
}
__device__ __forceinline__ float bf2f(unsigned short u){
  return __uint_as_float(((unsigned)u) << 16);
}

// --- K0: detect whether prgrph_mask arrived as 1-byte bool or 4-byte int32 ---
__global__ void k_detect(const uint8_t* m, int* flag){
  __shared__ int f;
  if(threadIdx.x==0) f = 0;
  __syncthreads();
  int loc = 0;
  for(int i = threadIdx.x; i < B_*T_*L_; i += blockDim.x){
    if((i&3)!=0 && m[i]!=0) loc = 1;   // int32 0/1 masks have zero bytes here
  }
  if(loc) atomicOr(&f, 1);
  __syncthreads();
  if(threadIdx.x==0) *flag = f;        // 1 => bool bytes, 0 => int32
}

// --- K1: per (b,t): enc row, SW = enc@Ww, KS = keys.enc, sent_mask ---
__global__ __launch_bounds__(128) void k_enc(const int* __restrict__ prg,
                                             const uint8_t* __restrict__ pm8,
                                             const float* __restrict__ emb,
                                             const float* __restrict__ pos,
                                             const float* __restrict__ Ww,
                                             const float* __restrict__ keys,
                                             float* __restrict__ W){
  const int flag = ((const int*)W)[FLAG_OFF];
  const int bt = blockIdx.x;
  const int b  = bt / T_;
  const int d  = threadIdx.x;
  __shared__ float keysl[K_*129];
  __shared__ float encl[D_];
  for(int r=0;r<K_;r++) keysl[r*129 + d] = keys[(b*K_ + r)*D_ + d];
  const int* pmi = (const int*)pm8;
  float acc = 0.f; int anym = 0;
  for(int l=0;l<L_;l++){
    int off = bt*L_ + l;
    int m = flag ? (int)pm8[off] : pmi[off];
    if(m){
      anym = 1;
      int idx = prg[off];
      acc += emb[idx*D_ + d] * pos[l*D_ + d];
    }
  }
  encl[d] = acc;
  W[ENC_OFF + bt*D_ + d] = acc;
  __syncthreads();
  float sw = 0.f;
  for(int e=0;e<D_;e++) sw += encl[e] * Ww[e*D_ + d];
  W[SW_OFF + bt*D_ + d] = sw;
  if(d < K_){
    float ks = 0.f;
    for(int dd=0;dd<D_;dd++) ks += keysl[d*129 + dd] * encl[dd];
    W[KS_OFF + bt*K_ + d] = ks;
  }
  if(d==0) W[SM_OFF + bt] = anym ? 1.f : 0.f;
}

// --- K2: KV = keys @ Vw ---
__global__ __launch_bounds__(128) void k_kv(const float* __restrict__ keys,
                                            const float* __restrict__ Vw,
                                            float* __restrict__ W){
  const int bk = blockIdx.x;
  const int d  = threadIdx.x;
  __shared__ float kr[D_];
  kr[d] = keys[bk*D_ + d];
  __syncthreads();
  float acc = 0.f;
  for(int e=0;e<D_;e++) acc += kr[e] * Vw[e*D_ + d];
  W[KV_OFF + bk*D_ + d] = acc;
}

// --- K3: MFMA scan. grid = 64 b x 4 kgroups; block = 1 wave (64 thr).
// Per block: 16 entities, full D=128.  Y[d_out][e] = sum_din U[din][dout] h[e][din]
// via mfma_16x16x32_bf16, U^T as A (in regs), h^T as B (repacked per step via LDS).
// C-layout: e = lane&15, d_out = 16*rt + 4*q + r  (q = lane>>4, r = acc reg).
__global__ __launch_bounds__(64,1) void k_scan(const float* __restrict__ W,
                                               const float* __restrict__ Uw,
                                               float* __restrict__ out){
  const int b    = blockIdx.x >> 2;
  const int kg   = blockIdx.x & 3;
  const int lane = threadIdx.x;
  const int e    = lane & 15;
  const int q    = lane >> 4;
  const int swz  = (e << 2) & 0x3C;     // XOR swizzle on u32-index bits 2..5

  __shared__ unsigned hrep[2048];       // [0..1023]=hi pairs, [1024..2047]=lo pairs

  // ---- one-time: U^T A-fragments.  A[row=e][k=8q+j] of tile(rt,kc) = Uw[32kc+8q+j][16rt+e]
  short8b ufrag[8][4];
  #pragma unroll
  for(int rt=0; rt<8; ++rt){
    #pragma unroll
    for(int kc=0; kc<4; ++kc){
      const float* src = &Uw[(32*kc + 8*q)*D_ + 16*rt + e];
      short8b f;
      #pragma unroll
      for(int j=0;j<8;++j) f[j] = (short)bfb(src[j*D_]);
      ufrag[rt][kc] = f;
    }
  }
  // kv in Y layout
  f32x4 kvv[8];
  {
    const float* kvp = &W[KV_OFF + (b*K_ + kg*16 + e)*D_ + 4*q];
    #pragma unroll
    for(int rt=0;rt<8;++rt) kvv[rt] = *(const f32x4*)&kvp[16*rt];
  }
  f32x4 hY[8];
  #pragma unroll
  for(int rt=0;rt<8;++rt) hY[rt] = 0.f;

  const float* ENC = &W[ENC_OFF + b*T_*D_];
  const float* SWg = &W[SW_OFF  + b*T_*D_];
  const float* KSg = &W[KS_OFF  + b*T_*K_];
  const float* SM  = &W[SM_OFF  + b*T_];

  #pragma unroll 1
  for(int t=0;t<T_;++t){
    if(SM[t] != 0.f){
      // --- gate: g = sigmoid(h.s + keys.s), s at this lane's 32 d positions
      f32x4 sv[8];
      const float* sp = &ENC[t*D_ + 4*q];
      #pragma unroll
      for(int rt=0;rt<8;++rt) sv[rt] = *(const f32x4*)&sp[16*rt];
      float ks = KSg[t*K_ + kg*16 + e];
      float gs = 0.f;
      #pragma unroll
      for(int rt=0;rt<8;++rt)
        gs += hY[rt][0]*sv[rt][0] + hY[rt][1]*sv[rt][1]
            + hY[rt][2]*sv[rt][2] + hY[rt][3]*sv[rt][3];
      gs += __shfl_xor(gs,16);
      gs += __shfl_xor(gs,32);
      float g = sigmoidf_(gs + ks);

      // --- repack h (Y layout) -> B-frag layout, hi + lo residual, via LDS
      #pragma unroll
      for(int rt=0;rt<8;++rt){
        float x0=hY[rt][0], x1=hY[rt][1], x2=hY[rt][2], x3=hY[rt][3];
        unsigned short h0=bfb(x0), h1=bfb(x1), h2=bfb(x2), h3=bfb(x3);
        unsigned hi0 = ((unsigned)h1<<16) | h0;
        unsigned hi1 = ((unsigned)h3<<16) | h2;
        unsigned short l0=bfb(x0-bf2f(h0)), l1=bfb(x1-bf2f(h1));
        unsigned short l2=bfb(x2-bf2f(h2)), l3=bfb(x3-bf2f(h3));
        unsigned lo0 = ((unsigned)l1<<16) | l0;
        unsigned lo1 = ((unsigned)l3<<16) | l2;
        int a = e*64 + ((8*rt + 2*q) ^ swz);
        uint2 wh; wh.x=hi0; wh.y=hi1;
        uint2 wl; wl.x=lo0; wl.y=lo1;
        *(uint2*)&hrep[a]        = wh;
        *(uint2*)&hrep[1024 + a] = wl;
      }
      __syncthreads();
      short8b bhi[4], blo[4];
      #pragma unroll
      for(int kc=0;kc<4;++kc){
        int a = e*64 + ((16*kc + 4*q) ^ swz);
        bhi[kc] = *(const short8b*)&hrep[a];
        blo[kc] = *(const short8b*)&hrep[1024 + a];
      }
      __syncthreads();   // reads done before next iteration's writes

      // --- Y = U^T h^T + kv
      f32x4 acc[8];
      #pragma unroll
      for(int rt=0;rt<8;++rt) acc[rt] = kvv[rt];
      #pragma unroll
      for(int rt=0;rt<8;++rt){
        #pragma unroll
        for(int kc=0;kc<4;++kc){
          acc[rt] = __builtin_amdgcn_mfma_f32_16x16x32_bf16(ufrag[rt][kc], bhi[kc], acc[rt], 0,0,0);
          acc[rt] = __builtin_amdgcn_mfma_f32_16x16x32_bf16(ufrag[rt][kc], blo[kc], acc[rt], 0,0,0);
        }
      }

      // --- x = Y + sW ; h_tilda = sigmoid(x); hn = h + g*h_tilda; L2-normalize
      f32x4 swv[8];
      const float* swp = &SWg[t*D_ + 4*q];
      #pragma unroll
      for(int rt=0;rt<8;++rt) swv[rt] = *(const f32x4*)&swp[16*rt];
      f32x4 hn[8];
      float nrm = 0.f;
      #pragma unroll
      for(int rt=0;rt<8;++rt){
        #pragma unroll
        for(int r=0;r<4;++r){
          float x  = acc[rt][r] + swv[rt][r];
          float ht = sigmoidf_(x);
          float v  = hY[rt][r] + g*ht;
          hn[rt][r] = v;
          nrm += v*v;
        }
      }
      nrm += __shfl_xor(nrm,16);
      nrm += __shfl_xor(nrm,32);
      float rn = rsqrtf(fmaxf(nrm, 1e-12f));
      #pragma unroll
      for(int rt=0;rt<8;++rt){
        #pragma unroll
        for(int r=0;r<4;++r) hY[rt][r] = hn[rt][r]*rn;
      }
    }
  }

  // --- write out: out[b, kg*16+e, 16rt+4q+r]
  float* op = &out[(b*K_ + kg*16 + e)*D_ + 4*q];
  #pragma unroll
  for(int rt=0;rt<8;++rt) *(f32x4*)&op[16*rt] = hY[rt];
}

extern "C" void kernel_launch(void* const* d_in, const int* in_sizes, int n_in,
                              void* d_out, int out_size, void* d_ws, size_t ws_size,
                              hipStream_t stream) {
  const int*     prg  = (const int*)d_in[0];
  const uint8_t* pm   = (const uint8_t*)d_in[1];
  const float*   emb  = (const float*)d_in[2];
  const float*   pos  = (const float*)d_in[3];
  const float*   Uw   = (const float*)d_in[4];
  const float*   Vw   = (const float*)d_in[5];
  const float*   Ww   = (const float*)d_in[6];
  const float*   keys = (const float*)d_in[7];
  float* W   = (float*)d_ws;
  float* out = (float*)d_out;

  hipLaunchKernelGGL(k_detect, dim3(1),      dim3(256), 0, stream, pm, (int*)d_ws);
  hipLaunchKernelGGL(k_enc,    dim3(B_*T_),  dim3(128), 0, stream, prg, pm, emb, pos, Ww, keys, W);
  hipLaunchKernelGGL(k_kv,     dim3(B_*K_),  dim3(128), 0, stream, keys, Vw, W);
  hipLaunchKernelGGL(k_scan,   dim3(B_*4),   dim3(64),  0, stream, W, Uw, out);
}

// Round 4
// 512.786 us; speedup vs baseline: 2.3389x; 1.5785x over previous
//
#include <hip/hip_runtime.h>
#include <hip/hip_bf16.h>
#include <stdint.h>

#define B_ 64
#define T_ 128
#define L_ 32
#define D_ 128
#define K_ 64

// workspace offsets in 4-byte units
#define FLAG_OFF 0                                 // 128 per-block detect flags
#define SM_OFF   256
#define ENC_OFF  (SM_OFF + B_*T_)                 // [B][T][D] f32
#define SW_OFF   (ENC_OFF + B_*T_*D_)             // [B][T][D] f32  (s @ Ww)
#define KS_OFF   (SW_OFF + B_*T_*D_)              // [B][T][K] f32  (keys . s)
#define KV_OFF   (KS_OFF + B_*T_*K_)              // [B][K][D] f32  (keys @ Vw)

typedef __attribute__((ext_vector_type(8))) short short8b;   // 8 bf16 = 4 VGPR
typedef __attribute__((ext_vector_type(4))) float f32x4;

__device__ __forceinline__ float sigmoidf_(float x){ return 1.0f/(1.0f + __expf(-x)); }

__device__ __forceinline__ unsigned short bfb(float x){
  __hip_bfloat16 h = __float2bfloat16(x);                    // RNE
  return __builtin_bit_cast(unsigned short, h);
}
__device__ __forceinline__ float bf2f(unsigned short u){
  return __uint_as_float(((unsigned)u) << 16);
}

// --- K0: parallel detect of prgrph_mask dtype (1-byte bool vs 4-byte int32).
// Reads exactly the guaranteed 256KB. int32 0/1 data has all bytes at %4!=0 zero.
__global__ __launch_bounds__(256) void k_detect(const uint8_t* __restrict__ m,
                                                int* __restrict__ flags){
  const unsigned* w = (const unsigned*)m;
  const int base = blockIdx.x * 512;
  unsigned acc = 0;
  acc |= w[base + threadIdx.x]       & 0xFFFFFF00u;
  acc |= w[base + threadIdx.x + 256] & 0xFFFFFF00u;
  int any = __syncthreads_or((int)(acc != 0u));
  if(threadIdx.x == 0) flags[blockIdx.x] = any;   // 1 => bool bytes, 0 => int32
}

// --- K1: per (b,t): enc row, SW = enc@Ww, KS = keys.enc, sent_mask ---
__global__ __launch_bounds__(128) void k_enc(const int* __restrict__ prg,
                                             const uint8_t* __restrict__ pm8,
                                             const float* __restrict__ emb,
                                             const float* __restrict__ pos,
                                             const float* __restrict__ Ww,
                                             const float* __restrict__ keys,
                                             float* __restrict__ W){
  const int bt = blockIdx.x;
  const int b  = bt / T_;
  const int d  = threadIdx.x;
  // OR-reduce the 128 detect flags (each of the 128 threads reads one word)
  int myf  = ((const int*)W)[FLAG_OFF + (d & 127)];
  int flag = __syncthreads_or(myf);
  __shared__ float keysl[K_*129];
  __shared__ float encl[D_];
  for(int r=0;r<K_;r++) keysl[r*129 + d] = keys[(b*K_ + r)*D_ + d];
  const int* pmi = (const int*)pm8;
  float acc = 0.f; int anym = 0;
  for(int l=0;l<L_;l++){
    int off = bt*L_ + l;
    int m = flag ? (int)pm8[off] : pmi[off];
    if(m){
      anym = 1;
      int idx = prg[off];
      acc += emb[idx*D_ + d] * pos[l*D_ + d];
    }
  }
  encl[d] = acc;
  W[ENC_OFF + bt*D_ + d] = acc;
  __syncthreads();
  float sw = 0.f;
  for(int e=0;e<D_;e++) sw += encl[e] * Ww[e*D_ + d];
  W[SW_OFF + bt*D_ + d] = sw;
  if(d < K_){
    float ks = 0.f;
    for(int dd=0;dd<D_;dd++) ks += keysl[d*129 + dd] * encl[dd];
    W[KS_OFF + bt*K_ + d] = ks;
  }
  if(d==0) W[SM_OFF + bt] = anym ? 1.f : 0.f;
}

// --- K2: KV = keys @ Vw ---
__global__ __launch_bounds__(128) void k_kv(const float* __restrict__ keys,
                                            const float* __restrict__ Vw,
                                            float* __restrict__ W){
  const int bk = blockIdx.x;
  const int d  = threadIdx.x;
  __shared__ float kr[D_];
  kr[d] = keys[bk*D_ + d];
  __syncthreads();
  float acc = 0.f;
  for(int e=0;e<D_;e++) acc += kr[e] * Vw[e*D_ + d];
  W[KV_OFF + bk*D_ + d] = acc;
}

// --- K3: MFMA scan, software-pipelined (prefetch step t+1 inputs during step t).
// grid = 64 b x 4 kgroups; block = 1 wave. C-layout: e = lane&15, d_out = 16rt+4q+r.
__global__ __launch_bounds__(64,1) void k_scan(const float* __restrict__ W,
                                               const float* __restrict__ Uw,
                                               float* __restrict__ out){
  const int b    = blockIdx.x >> 2;
  const int kg   = blockIdx.x & 3;
  const int lane = threadIdx.x;
  const int e    = lane & 15;
  const int q    = lane >> 4;
  const int swz  = (e << 2) & 0x3C;     // XOR swizzle on u32-index bits 2..5

  __shared__ unsigned hrep[2048];       // [0..1023]=hi pairs, [1024..2047]=lo pairs

  // ---- one-time: U^T A-fragments.  A[row=e][k=8q+j] of tile(rt,kc) = Uw[32kc+8q+j][16rt+e]
  short8b ufrag[8][4];
  #pragma unroll
  for(int rt=0; rt<8; ++rt){
    #pragma unroll
    for(int kc=0; kc<4; ++kc){
      const float* src = &Uw[(32*kc + 8*q)*D_ + 16*rt + e];
      short8b f;
      #pragma unroll
      for(int j=0;j<8;++j) f[j] = (short)bfb(src[j*D_]);
      ufrag[rt][kc] = f;
    }
  }
  // kv in Y layout
  f32x4 kvv[8];
  {
    const float* kvp = &W[KV_OFF + (b*K_ + kg*16 + e)*D_ + 4*q];
    #pragma unroll
    for(int rt=0;rt<8;++rt) kvv[rt] = *(const f32x4*)&kvp[16*rt];
  }
  f32x4 hY[8];
  #pragma unroll
  for(int rt=0;rt<8;++rt) hY[rt] = 0.f;

  const float* ENC = &W[ENC_OFF + b*T_*D_];
  const float* SWg = &W[SW_OFF  + b*T_*D_];
  const float* KSg = &W[KS_OFF  + b*T_*K_];
  const float* SM  = &W[SM_OFF  + b*T_];

  auto loadstep = [&](int t, f32x4 (&sv)[8], f32x4 (&sw)[8], float& ks, float& sm){
    const float* sp = &ENC[t*D_ + 4*q];
    const float* wp = &SWg[t*D_ + 4*q];
    #pragma unroll
    for(int rt=0;rt<8;++rt){
      sv[rt] = *(const f32x4*)&sp[16*rt];
      sw[rt] = *(const f32x4*)&wp[16*rt];
    }
    ks = KSg[t*K_ + kg*16 + e];
    sm = SM[t];
  };

  auto dostep = [&](const f32x4 (&sv)[8], const f32x4 (&swv)[8], float ks, float sm){
    if(sm != 0.f){
      // gate
      float gs = 0.f;
      #pragma unroll
      for(int rt=0;rt<8;++rt)
        gs += hY[rt][0]*sv[rt][0] + hY[rt][1]*sv[rt][1]
            + hY[rt][2]*sv[rt][2] + hY[rt][3]*sv[rt][3];
      gs += __shfl_xor(gs,16);
      gs += __shfl_xor(gs,32);
      float g = sigmoidf_(gs + ks);

      // repack h (Y layout) -> B-frag layout, hi + lo residual, via LDS
      #pragma unroll
      for(int rt=0;rt<8;++rt){
        float x0=hY[rt][0], x1=hY[rt][1], x2=hY[rt][2], x3=hY[rt][3];
        unsigned short h0=bfb(x0), h1=bfb(x1), h2=bfb(x2), h3=bfb(x3);
        unsigned hi0 = ((unsigned)h1<<16) | h0;
        unsigned hi1 = ((unsigned)h3<<16) | h2;
        unsigned short l0=bfb(x0-bf2f(h0)), l1=bfb(x1-bf2f(h1));
        unsigned short l2=bfb(x2-bf2f(h2)), l3=bfb(x3-bf2f(h3));
        unsigned lo0 = ((unsigned)l1<<16) | l0;
        unsigned lo1 = ((unsigned)l3<<16) | l2;
        int a = e*64 + ((8*rt + 2*q) ^ swz);
        uint2 wh; wh.x=hi0; wh.y=hi1;
        uint2 wl; wl.x=lo0; wl.y=lo1;
        *(uint2*)&hrep[a]        = wh;
        *(uint2*)&hrep[1024 + a] = wl;
      }
      __syncthreads();
      short8b bhi[4], blo[4];
      #pragma unroll
      for(int kc=0;kc<4;++kc){
        int a = e*64 + ((16*kc + 4*q) ^ swz);
        bhi[kc] = *(const short8b*)&hrep[a];
        blo[kc] = *(const short8b*)&hrep[1024 + a];
      }
      __syncthreads();   // reads done before next step's writes

      // Y = U^T h^T + kv
      f32x4 acc[8];
      #pragma unroll
      for(int rt=0;rt<8;++rt) acc[rt] = kvv[rt];
      #pragma unroll
      for(int rt=0;rt<8;++rt){
        #pragma unroll
        for(int kc=0;kc<4;++kc){
          acc[rt] = __builtin_amdgcn_mfma_f32_16x16x32_bf16(ufrag[rt][kc], bhi[kc], acc[rt], 0,0,0);
          acc[rt] = __builtin_amdgcn_mfma_f32_16x16x32_bf16(ufrag[rt][kc], blo[kc], acc[rt], 0,0,0);
        }
      }

      // epilogue: x = Y + sW ; hn = h + g*sigmoid(x); L2-normalize
      f32x4 hn[8];
      float nrm = 0.f;
      #pragma unroll
      for(int rt=0;rt<8;++rt){
        #pragma unroll
        for(int r=0;r<4;++r){
          float x  = acc[rt][r] + swv[rt][r];
          float ht = sigmoidf_(x);
          float v  = hY[rt][r] + g*ht;
          hn[rt][r] = v;
          nrm += v*v;
        }
      }
      nrm += __shfl_xor(nrm,16);
      nrm += __shfl_xor(nrm,32);
      float rn = rsqrtf(fmaxf(nrm, 1e-12f));
      #pragma unroll
      for(int rt=0;rt<8;++rt){
        #pragma unroll
        for(int r=0;r<4;++r) hY[rt][r] = hn[rt][r]*rn;
      }
    }
  };

  // software pipeline: named A/B buffers, loop unrolled by 2 (no runtime-indexed regs)
  f32x4 svA[8], swA[8], svB[8], swB[8];
  float ksA, smA, ksB, smB;
  loadstep(0, svA, swA, ksA, smA);
  #pragma unroll 1
  for(int t=0; t<T_; t+=2){
    loadstep(t+1, svB, swB, ksB, smB);      // prefetch t+1 while computing t
    dostep(svA, swA, ksA, smA);
    int t2 = (t+2 < T_) ? (t+2) : 0;        // tail: harmless dummy reload
    loadstep(t2, svA, swA, ksA, smA);       // prefetch t+2 while computing t+1
    dostep(svB, swB, ksB, smB);
  }

  // write out: out[b, kg*16+e, 16rt+4q+r]
  float* op = &out[(b*K_ + kg*16 + e)*D_ + 4*q];
  #pragma unroll
  for(int rt=0;rt<8;++rt) *(f32x4*)&op[16*rt] = hY[rt];
}

extern "C" void kernel_launch(void* const* d_in, const int* in_sizes, int n_in,
                              void* d_out, int out_size, void* d_ws, size_t ws_size,
                              hipStream_t stream) {
  const int*     prg  = (const int*)d_in[0];
  const uint8_t* pm   = (const uint8_t*)d_in[1];
  const float*   emb  = (const float*)d_in[2];
  const float*   pos  = (const float*)d_in[3];
  const float*   Uw   = (const float*)d_in[4];
  const float*   Vw   = (const float*)d_in[5];
  const float*   Ww   = (const float*)d_in[6];
  const float*   keys = (const float*)d_in[7];
  float* W   = (float*)d_ws;
  float* out = (float*)d_out;

  hipLaunchKernelGGL(k_detect, dim3(128),    dim3(256), 0, stream, pm, (int*)d_ws + FLAG_OFF);
  hipLaunchKernelGGL(k_enc,    dim3(B_*T_),  dim3(128), 0, stream, prg, pm, emb, pos, Ww, keys, W);
  hipLaunchKernelGGL(k_kv,     dim3(B_*K_),  dim3(128), 0, stream, keys, Vw, W);
  hipLaunchKernelGGL(k_scan,   dim3(B_*4),   dim3(64),  0, stream, W, Uw, out);
}